// Round 1
// baseline (5390.988 us; speedup 1.0000x reference)
//
#include <hip/hip_runtime.h>
#include <hip/hip_bf16.h>

// Problem constants (fixed by the reference)
constexpr int B  = 4;
constexpr int N  = 2048;
constexpr int D  = 1024;
constexpr int H  = 16;
constexpr int HD = 64;            // head dim
constexpr int M  = B * N;         // 8192 rows
constexpr int K3 = 3 * D;         // 3072

// ---------------------------------------------------------------------------
// Tiled fp32 GEMM: C[Md,Nd] = A[Md,Kd] @ Bm[Kd,Nd] (+ bias[col] if non-null)
// BM=BN=64, BK=16, 256 threads, each thread computes a 4x4 sub-block.
// LDS padded +4 (keeps float4-friendly alignment, <=2-way bank aliasing=free).
// ---------------------------------------------------------------------------
template <int BM, int BN, int BK>
__global__ __launch_bounds__(256)
void gemm_f32(const float* __restrict__ A, const float* __restrict__ Bm,
              float* __restrict__ C, const float* __restrict__ bias,
              int Md, int Nd, int Kd) {
    __shared__ float As[BK][BM + 4];   // stored transposed: As[k][m]
    __shared__ float Bs[BK][BN + 4];

    const int tid  = threadIdx.x;
    const int tx   = tid & 15;         // n-group
    const int ty   = tid >> 4;         // m-group
    const int row0 = blockIdx.y * BM;
    const int col0 = blockIdx.x * BN;

    float acc[4][4] = {};

    for (int k0 = 0; k0 < Kd; k0 += BK) {
        // Stage A tile (BM x BK), transposed into As[k][m]
        #pragma unroll
        for (int j = 0; j < (BM * BK) / 256; ++j) {
            int i = tid + 256 * j;
            int m = i / BK, k = i % BK;
            As[k][m] = A[(size_t)(row0 + m) * Kd + (k0 + k)];
        }
        // Stage B tile (BK x BN)
        #pragma unroll
        for (int j = 0; j < (BK * BN) / 256; ++j) {
            int i = tid + 256 * j;
            int k = i / BN, n = i % BN;
            Bs[k][n] = Bm[(size_t)(k0 + k) * Nd + (col0 + n)];
        }
        __syncthreads();

        #pragma unroll
        for (int k = 0; k < BK; ++k) {
            float a[4], bb[4];
            #pragma unroll
            for (int i = 0; i < 4; ++i) a[i]  = As[k][ty * 4 + i];
            #pragma unroll
            for (int i = 0; i < 4; ++i) bb[i] = Bs[k][tx * 4 + i];
            #pragma unroll
            for (int i = 0; i < 4; ++i)
                #pragma unroll
                for (int j = 0; j < 4; ++j)
                    acc[i][j] = fmaf(a[i], bb[j], acc[i][j]);
        }
        __syncthreads();
    }

    #pragma unroll
    for (int i = 0; i < 4; ++i) {
        const size_t r = row0 + ty * 4 + i;
        #pragma unroll
        for (int j = 0; j < 4; ++j) {
            const int c = col0 + tx * 4 + j;
            float v = acc[i][j];
            if (bias) v += bias[c];
            C[r * (size_t)Nd + c] = v;
        }
    }
}

// ---------------------------------------------------------------------------
// Flash attention, fp32. qkv layout: [B*N, 3*D] with col = which*D + h*HD + d.
// Grid: (N/16, B*H). Block: 256 thr = 4 waves; each wave owns 4 q-rows.
// Per wave: lane j holds the score for key (tile_base + j); output dim = lane.
// K/V tiles (64 keys x 64 dims) staged in LDS with +1 pad -> 2-way (free).
// ---------------------------------------------------------------------------
__global__ __launch_bounds__(256)
void attn_f32(const float* __restrict__ qkv, float* __restrict__ out) {
    constexpr int ROWS = 16;   // q rows per block
    constexpr int R    = 4;    // q rows per wave
    constexpr int KT   = 64;   // keys per tile

    __shared__ float qs[ROWS][HD];
    __shared__ float Kt[KT][HD + 1];
    __shared__ float Vt[KT][HD + 1];

    const int tid  = threadIdx.x;
    const int lane = tid & 63;
    const int w    = tid >> 6;
    const int bh   = blockIdx.y;
    const int b    = bh / H;
    const int h    = bh % H;
    const int n0   = blockIdx.x * ROWS;
    const size_t rowbase = (size_t)b * N * K3;

    // Stage the block's Q rows (broadcast-read later, no pad needed)
    #pragma unroll
    for (int j = 0; j < (ROWS * HD) / 256; ++j) {
        int i = tid + 256 * j;
        int r = i / HD, d = i % HD;
        qs[r][d] = qkv[rowbase + (size_t)(n0 + r) * K3 + h * HD + d];
    }

    float mrun[R], lrun[R], o[R];
    #pragma unroll
    for (int rr = 0; rr < R; ++rr) { mrun[rr] = -1e30f; lrun[rr] = 0.f; o[rr] = 0.f; }

    for (int kt = 0; kt < N; kt += KT) {
        __syncthreads();   // protect previous iter's reads (and first-iter qs)
        #pragma unroll
        for (int j = 0; j < (KT * HD) / 256; ++j) {
            int i = tid + 256 * j;
            int r = i / HD, d = i % HD;
            const size_t krow = rowbase + (size_t)(kt + r) * K3 + h * HD;
            Kt[r][d] = qkv[krow + D     + d];
            Vt[r][d] = qkv[krow + 2 * D + d];
        }
        __syncthreads();

        float p[R];
        #pragma unroll
        for (int rr = 0; rr < R; ++rr) {
            const float* q = qs[w * R + rr];
            float s0 = 0.f, s1 = 0.f;                 // 2 chains for ILP
            #pragma unroll
            for (int d = 0; d < HD; d += 2) {
                s0 = fmaf(q[d],     Kt[lane][d],     s0);
                s1 = fmaf(q[d + 1], Kt[lane][d + 1], s1);
            }
            float s = (s0 + s1) * 0.125f;             // hd^-0.5 = 1/8

            float mt = s;
            #pragma unroll
            for (int off = 32; off > 0; off >>= 1)
                mt = fmaxf(mt, __shfl_xor(mt, off));
            const float mn    = fmaxf(mrun[rr], mt);
            const float alpha = __expf(mrun[rr] - mn);
            const float pe    = __expf(s - mn);
            float ps = pe;
            #pragma unroll
            for (int off = 32; off > 0; off >>= 1)
                ps += __shfl_xor(ps, off);
            lrun[rr] = lrun[rr] * alpha + ps;
            o[rr]   *= alpha;
            mrun[rr] = mn;
            p[rr]    = pe;
        }

        #pragma unroll 8
        for (int j = 0; j < KT; ++j) {
            const float v = Vt[j][lane];
            #pragma unroll
            for (int rr = 0; rr < R; ++rr)
                o[rr] = fmaf(__shfl(p[rr], j), v, o[rr]);
        }
    }

    #pragma unroll
    for (int rr = 0; rr < R; ++rr) {
        const int n = n0 + w * R + rr;
        out[((size_t)b * N + n) * D + h * HD + lane] = o[rr] / lrun[rr];
    }
}

// ---------------------------------------------------------------------------
// Launch: qkv GEMM -> flash attention -> proj GEMM (+bias)
// Workspace: qkv [M,3D] fp32 (96 MiB) + attn_out [M,D] fp32 (32 MiB) = 128 MiB
// ---------------------------------------------------------------------------
extern "C" void kernel_launch(void* const* d_in, const int* in_sizes, int n_in,
                              void* d_out, int out_size, void* d_ws, size_t ws_size,
                              hipStream_t stream) {
    const float* x     = (const float*)d_in[0];
    const float* Wqkv  = (const float*)d_in[1];
    const float* Wproj = (const float*)d_in[2];
    const float* bproj = (const float*)d_in[3];
    float* outp = (float*)d_out;

    float* qkv      = (float*)d_ws;                 // M x 3D
    float* attn_out = qkv + (size_t)M * K3;         // M x D

    // 1) qkv = x @ W_qkv          [8192,1024]@[1024,3072]
    dim3 g1(K3 / 64, M / 64);
    gemm_f32<64, 64, 16><<<g1, 256, 0, stream>>>(x, Wqkv, qkv, nullptr, M, K3, D);

    // 2) flash attention per (b,h)
    dim3 g2(N / 16, B * H);
    attn_f32<<<g2, 256, 0, stream>>>(qkv, attn_out);

    // 3) out = attn_out @ W_proj + b_proj   [8192,1024]@[1024,1024]
    dim3 g3(D / 64, M / 64);
    gemm_f32<64, 64, 16><<<g3, 256, 0, stream>>>(attn_out, Wproj, outp, bproj, M, D, D);
}

// Round 3
// 1252.952 us; speedup vs baseline: 4.3026x; 4.3026x over previous
//
#include <hip/hip_runtime.h>
#include <hip/hip_bf16.h>

// Problem constants (fixed by the reference)
constexpr int B  = 4;
constexpr int N  = 2048;
constexpr int D  = 1024;
constexpr int H  = 16;
constexpr int HD = 64;            // head dim
constexpr int M  = B * N;         // 8192 rows
constexpr int K3 = 3 * D;         // 3072

typedef __attribute__((ext_vector_type(8))) short  short8v;  // 8 bf16 in 4 VGPRs
typedef __attribute__((ext_vector_type(4))) float  f32x4;
typedef __attribute__((ext_vector_type(4))) unsigned short us4;

__device__ inline unsigned short f2bf(float f) {   // fp32 -> bf16 bits, RNE
    union { float f; unsigned u; } x{f};
    unsigned r = x.u + 0x7fffu + ((x.u >> 16) & 1u);
    return (unsigned short)(r >> 16);
}

// ---------------------------------------------------------------------------
// Tiled fp32 GEMM (VALU): C = A@B (+bias). OutT = float or ushort(bf16 store).
// ---------------------------------------------------------------------------
template <int BM, int BN, int BK, typename OutT>
__global__ __launch_bounds__(256)
void gemm_f32(const float* __restrict__ A, const float* __restrict__ Bm,
              OutT* __restrict__ C, const float* __restrict__ bias,
              int Md, int Nd, int Kd) {
    __shared__ float As[BK][BM + 4];   // transposed: As[k][m]
    __shared__ float Bs[BK][BN + 4];

    const int tid  = threadIdx.x;
    const int tx   = tid & 15;
    const int ty   = tid >> 4;
    const int row0 = blockIdx.y * BM;
    const int col0 = blockIdx.x * BN;

    float acc[4][4] = {};

    for (int k0 = 0; k0 < Kd; k0 += BK) {
        #pragma unroll
        for (int j = 0; j < (BM * BK) / 256; ++j) {
            int i = tid + 256 * j;
            int m = i / BK, k = i % BK;
            As[k][m] = A[(size_t)(row0 + m) * Kd + (k0 + k)];
        }
        #pragma unroll
        for (int j = 0; j < (BK * BN) / 256; ++j) {
            int i = tid + 256 * j;
            int k = i / BN, n = i % BN;
            Bs[k][n] = Bm[(size_t)(k0 + k) * Nd + (col0 + n)];
        }
        __syncthreads();

        #pragma unroll
        for (int k = 0; k < BK; ++k) {
            float a[4], bb[4];
            #pragma unroll
            for (int i = 0; i < 4; ++i) a[i]  = As[k][ty * 4 + i];
            #pragma unroll
            for (int i = 0; i < 4; ++i) bb[i] = Bs[k][tx * 4 + i];
            #pragma unroll
            for (int i = 0; i < 4; ++i)
                #pragma unroll
                for (int j = 0; j < 4; ++j)
                    acc[i][j] = fmaf(a[i], bb[j], acc[i][j]);
        }
        __syncthreads();
    }

    #pragma unroll
    for (int i = 0; i < 4; ++i) {
        const size_t r = row0 + ty * 4 + i;
        #pragma unroll
        for (int j = 0; j < 4; ++j) {
            const int c = col0 + tx * 4 + j;
            float v = acc[i][j];
            if (bias) v += bias[c];
            if constexpr (sizeof(OutT) == 2)
                C[r * (size_t)Nd + c] = (OutT)f2bf(v);
            else
                C[r * (size_t)Nd + c] = (OutT)v;
        }
    }
}

// ---------------------------------------------------------------------------
// V transpose: qkv_bf V-section [b,n, 2D + h*64 + d] -> Vt[bh][d][n]  (bf16)
// ---------------------------------------------------------------------------
__global__ __launch_bounds__(256)
void transposeV(const unsigned short* __restrict__ qkvb, unsigned short* __restrict__ Vt) {
    __shared__ unsigned short t[64][68];
    const int bh = blockIdx.y, b = bh >> 4, h = bh & 15;
    const int n0 = blockIdx.x * 64;
    const int tid = threadIdx.x;

    #pragma unroll
    for (int i = 0; i < 4; ++i) {
        int key = (tid >> 4) + 16 * i, d0 = (tid & 15) * 4;
        us4 v = *(const us4*)(qkvb + (size_t)(b * N + n0 + key) * K3 + 2 * D + h * 64 + d0);
        *(us4*)&t[key][d0] = v;
    }
    __syncthreads();
    #pragma unroll
    for (int i = 0; i < 4; ++i) {
        int d = (tid >> 4) + 16 * i, k0 = (tid & 15) * 4;
        us4 v = { t[k0][d], t[k0 + 1][d], t[k0 + 2][d], t[k0 + 3][d] };
        *(us4*)(Vt + ((size_t)bh * 64 + d) * N + n0 + k0) = v;
    }
}

// ---------------------------------------------------------------------------
// MFMA bf16 flash attention.
// Grid (N/64, B*H), 256 thr = 4 waves; each wave owns 16 q-rows.
// K-tile = 64 keys. LDS tiles XOR-swizzled: 16B-slot ^= (row&7).
// Fragment layout (16x16x32): A row=lane&15,k=8*(lane>>4)+e; B col=lane&15,
// same k; C/D col=lane&15,row=4*(lane>>4)+reg (m89-verified).
// ---------------------------------------------------------------------------
__global__ __launch_bounds__(256)
void attn_mfma(const unsigned short* __restrict__ qkvb,
               const unsigned short* __restrict__ Vt,
               float* __restrict__ out) {
    __shared__ unsigned short K_lds[64 * 64];   // [key][d] swizzled
    __shared__ unsigned short V_lds[64 * 64];   // [d][key] swizzled (from Vt)
    __shared__ unsigned short P_lds[4 * 16 * 64]; // per-wave [q][key] swizzled

    const int tid  = threadIdx.x;
    const int lane = tid & 63;
    const int w    = tid >> 6;
    const int lr   = lane & 15;
    const int lg   = lane >> 4;          // 0..3
    const int bh   = blockIdx.y, b = bh >> 4, h = bh & 15;
    const int q0   = blockIdx.x * 64;

    // Q A-fragments (2 k-steps of 32 over head dim 64), straight from global
    short8v qa[2];
    {
        const unsigned short* qrow =
            qkvb + (size_t)(b * N + q0 + w * 16 + lr) * K3 + h * 64 + lg * 8;
        qa[0] = *(const short8v*)(qrow);
        qa[1] = *(const short8v*)(qrow + 32);
    }

    f32x4 oacc[4] = {};
    float mrow[4], lrow[4];
    #pragma unroll
    for (int r = 0; r < 4; ++r) { mrow[r] = -1e30f; lrow[r] = 0.f; }

    const unsigned short* kbase  = qkvb + (size_t)b * N * K3 + D + h * 64;
    const unsigned short* vtbase = Vt + (size_t)bh * 64 * N;

    for (int kt = 0; kt < N; kt += 64) {
        __syncthreads();                      // previous tile fully consumed
        #pragma unroll
        for (int i = 0; i < 2; ++i) {
            int cc = tid + 256 * i;           // 0..511
            int row = cc >> 3, blk = cc & 7;  // 8 ushort per chunk
            short8v kv = *(const short8v*)(kbase + (size_t)(kt + row) * K3 + blk * 8);
            *(short8v*)(K_lds + row * 64 + ((blk ^ (row & 7)) * 8)) = kv;
            short8v vv = *(const short8v*)(vtbase + (size_t)row * N + kt + blk * 8);
            *(short8v*)(V_lds + row * 64 + ((blk ^ (row & 7)) * 8)) = vv;
        }
        __syncthreads();

        // ---- S = Q @ K^T  (4 key-subtiles x 2 k-steps) ----
        f32x4 sacc[4] = {};
        #pragma unroll
        for (int sj = 0; sj < 4; ++sj) {
            const int key = 16 * sj + lr;
            #pragma unroll
            for (int ks = 0; ks < 2; ++ks) {
                short8v kb = *(const short8v*)(K_lds + key * 64 +
                                               (((4 * ks + lg) ^ (key & 7)) * 8));
                sacc[sj] = __builtin_amdgcn_mfma_f32_16x16x32_bf16(qa[ks], kb, sacc[sj], 0, 0, 0);
            }
        }

        // ---- online softmax (scale 1/8 applied inside exp) ----
        float pm[4], alpha[4];
        #pragma unroll
        for (int r = 0; r < 4; ++r) {
            float mt = fmaxf(fmaxf(sacc[0][r], sacc[1][r]), fmaxf(sacc[2][r], sacc[3][r]));
            #pragma unroll
            for (int off = 8; off >= 1; off >>= 1)
                mt = fmaxf(mt, __shfl_xor(mt, off));
            pm[r] = mt;
        }
        #pragma unroll
        for (int r = 0; r < 4; ++r) {
            float mn = fmaxf(mrow[r], pm[r]);
            alpha[r] = __expf((mrow[r] - mn) * 0.125f);
            mrow[r] = mn;
        }
        float psum[4] = {0.f, 0.f, 0.f, 0.f};
        #pragma unroll
        for (int sj = 0; sj < 4; ++sj) {
            #pragma unroll
            for (int r = 0; r < 4; ++r) {
                float p = __expf((sacc[sj][r] - mrow[r]) * 0.125f);
                psum[r] += p;
                const int row = 4 * lg + r, key = 16 * sj + lr;
                P_lds[w * 1024 + row * 64 + (((key >> 3) ^ (row & 7)) * 8) + (key & 7)] = f2bf(p);
            }
        }
        #pragma unroll
        for (int r = 0; r < 4; ++r) {
            float ps = psum[r];
            #pragma unroll
            for (int off = 8; off >= 1; off >>= 1)
                ps += __shfl_xor(ps, off);
            lrow[r] = lrow[r] * alpha[r] + ps;
            #pragma unroll
            for (int dj = 0; dj < 4; ++dj) oacc[dj][r] *= alpha[r];
        }

        // ---- O += P @ V  (2 k-steps over keys, 4 d-subtiles) ----
        #pragma unroll
        for (int ks = 0; ks < 2; ++ks) {
            short8v pa = *(const short8v*)(P_lds + w * 1024 + lr * 64 +
                                           (((4 * ks + lg) ^ (lr & 7)) * 8));
            #pragma unroll
            for (int dj = 0; dj < 4; ++dj) {
                const int d = 16 * dj + lr;
                short8v vb = *(const short8v*)(V_lds + d * 64 +
                                               (((4 * ks + lg) ^ (d & 7)) * 8));
                oacc[dj] = __builtin_amdgcn_mfma_f32_16x16x32_bf16(pa, vb, oacc[dj], 0, 0, 0);
            }
        }
    }

    // epilogue: divide by l, store fp32
    #pragma unroll
    for (int r = 0; r < 4; ++r) {
        const float inv = 1.0f / lrow[r];
        const int q = q0 + w * 16 + 4 * lg + r;
        #pragma unroll
        for (int dj = 0; dj < 4; ++dj)
            out[((size_t)b * N + q) * D + h * 64 + 16 * dj + lr] = oacc[dj][r] * inv;
    }
}

// ---------------------------------------------------------------------------
// qkv GEMM (bf16 out) -> V transpose -> MFMA flash attn -> proj GEMM (fp32)
// ws: qkv_bf 48MB + Vt 16MB + attn_out 32MB = 96MB
// ---------------------------------------------------------------------------
extern "C" void kernel_launch(void* const* d_in, const int* in_sizes, int n_in,
                              void* d_out, int out_size, void* d_ws, size_t ws_size,
                              hipStream_t stream) {
    const float* x     = (const float*)d_in[0];
    const float* Wqkv  = (const float*)d_in[1];
    const float* Wproj = (const float*)d_in[2];
    const float* bproj = (const float*)d_in[3];
    float* outp = (float*)d_out;

    unsigned short* qkv_bf = (unsigned short*)d_ws;                 // M x 3D bf16
    unsigned short* Vtp    = qkv_bf + (size_t)M * K3;               // B*H*HD*N bf16
    float* attn_out        = (float*)(Vtp + (size_t)B * H * HD * N);// M x D fp32

    dim3 g1(K3 / 64, M / 64);
    gemm_f32<64, 64, 16, unsigned short><<<g1, 256, 0, stream>>>(x, Wqkv, qkv_bf, nullptr, M, K3, D);

    dim3 g2(N / 64, B * H);
    transposeV<<<g2, 256, 0, stream>>>(qkv_bf, Vtp);

    dim3 g3(N / 64, B * H);
    attn_mfma<<<g3, 256, 0, stream>>>(qkv_bf, Vtp, attn_out);

    dim3 g4(D / 64, M / 64);
    gemm_f32<64, 64, 16, float><<<g4, 256, 0, stream>>>(attn_out, Wproj, outp, bproj, M, D, D);
}

// Round 5
// 416.485 us; speedup vs baseline: 12.9440x; 3.0084x over previous
//
#include <hip/hip_runtime.h>
#include <hip/hip_bf16.h>

// Problem constants (fixed by the reference)
constexpr int B  = 4;
constexpr int N  = 2048;
constexpr int D  = 1024;
constexpr int H  = 16;
constexpr int HD = 64;            // head dim
constexpr int M  = B * N;         // 8192 rows
constexpr int K3 = 3 * D;         // 3072

typedef __attribute__((ext_vector_type(8))) short  short8v;  // 8 bf16 in 4 VGPRs
typedef __attribute__((ext_vector_type(4))) float  f32x4;
typedef __attribute__((ext_vector_type(4))) unsigned short us4;

__device__ inline unsigned short f2bf(float f) {   // fp32 -> bf16 bits, RNE
    union { float f; unsigned u; } x{f};
    unsigned r = x.u + 0x7fffu + ((x.u >> 16) & 1u);
    return (unsigned short)(r >> 16);
}

__device__ __forceinline__ void gload_lds16(const unsigned short* g, unsigned short* l) {
    __builtin_amdgcn_global_load_lds(
        (const __attribute__((address_space(1))) void*)g,
        (__attribute__((address_space(3))) void*)l, 16, 0, 0);
}

// ---------------------------------------------------------------------------
// fp32 -> bf16 elementwise (8 elems/thread)
// ---------------------------------------------------------------------------
__global__ __launch_bounds__(256)
void cvt_bf16(const float* __restrict__ in, unsigned short* __restrict__ outp, int n8) {
    int i = blockIdx.x * 256 + threadIdx.x;
    if (i >= n8) return;
    f32x4 a = *(const f32x4*)(in + (size_t)i * 8);
    f32x4 b = *(const f32x4*)(in + (size_t)i * 8 + 4);
    short8v v;
    #pragma unroll
    for (int j = 0; j < 4; ++j) { v[j] = (short)f2bf(a[j]); v[4 + j] = (short)f2bf(b[j]); }
    *(short8v*)(outp + (size_t)i * 8) = v;
}

// ---------------------------------------------------------------------------
// W [Kd][Nd] fp32  ->  Wt [Nd][Kd] bf16   (64x64 tiles via LDS)
// ---------------------------------------------------------------------------
__global__ __launch_bounds__(256)
void transpose_w(const float* __restrict__ W, unsigned short* __restrict__ Wt,
                 int Kd, int Nd) {
    __shared__ unsigned short t[64][68];
    const int k0 = blockIdx.y * 64, n0 = blockIdx.x * 64;
    const int tid = threadIdx.x;
    #pragma unroll
    for (int i = 0; i < 4; ++i) {
        int k = (tid >> 4) + 16 * i, nn = (tid & 15) * 4;
        f32x4 v = *(const f32x4*)(W + (size_t)(k0 + k) * Nd + n0 + nn);
        #pragma unroll
        for (int j = 0; j < 4; ++j) t[k][nn + j] = f2bf(v[j]);
    }
    __syncthreads();
    #pragma unroll
    for (int i = 0; i < 4; ++i) {
        int n = (tid >> 4) + 16 * i, kk = (tid & 15) * 4;
        us4 v = { t[kk][n], t[kk + 1][n], t[kk + 2][n], t[kk + 3][n] };
        *(us4*)(Wt + (size_t)(n0 + n) * Kd + k0 + kk) = v;
    }
}

// ---------------------------------------------------------------------------
// bf16 MFMA GEMM (m97 structure): C[Md][Nd] = A[Md][Kd] @ Bt[Nd][Kd]^T (+bias)
// 128x128 tile, BK=64, 256 thr = 4 waves (2x2), wave = 64x64 quadrant.
// LDS: linear dest for global_load_lds; swizzle via permuted GLOBAL source
// (rule 21), ds_read uses slot^(row&7) -> conflict-free b128.
// ---------------------------------------------------------------------------
template <bool BIAS, typename OutT>
__global__ __launch_bounds__(256)
void gemm_bf16(const unsigned short* __restrict__ A,   // [Md][Kd]
               const unsigned short* __restrict__ Bt,  // [Nd][Kd]
               OutT* __restrict__ C, const float* __restrict__ bias,
               int Md, int Nd, int Kd) {
    __shared__ unsigned short As[128 * 64];
    __shared__ unsigned short Bs[128 * 64];

    const int tid  = threadIdx.x;
    const int lane = tid & 63;
    const int w    = tid >> 6;
    const int lr   = lane & 15;
    const int lg   = lane >> 4;
    const int wm   = w >> 1, wn = w & 1;
    const int row0 = blockIdx.y * 128;
    const int col0 = blockIdx.x * 128;

    f32x4 acc[4][4] = {};   // [mi][ni]

    for (int k0 = 0; k0 < Kd; k0 += 64) {
        // ---- stage A,B tiles (16KB each) via global_load_lds w=16 ----
        #pragma unroll
        for (int it = 0; it < 4; ++it) {
            const int c    = (it * 4 + w) * 64 + lane;   // chunk 0..1023
            const int row  = c >> 3, slot = c & 7;
            const int gs   = (slot ^ (row & 7)) * 8;     // pre-swizzled source
            gload_lds16(A  + (size_t)(row0 + row) * Kd + k0 + gs, As + c * 8);
            gload_lds16(Bt + (size_t)(col0 + row) * Kd + k0 + gs, Bs + c * 8);
        }
        asm volatile("s_waitcnt vmcnt(0)" ::: "memory");
        __syncthreads();

        // ---- fragments (swizzled ds_read_b128) ----
        short8v af[4][2], bfr[4][2];
        #pragma unroll
        for (int mi = 0; mi < 4; ++mi) {
            const int row = wm * 64 + mi * 16 + lr;
            #pragma unroll
            for (int kk = 0; kk < 2; ++kk)
                af[mi][kk] = *(const short8v*)(As + row * 64 + (((kk * 4 + lg) ^ (row & 7)) * 8));
        }
        #pragma unroll
        for (int ni = 0; ni < 4; ++ni) {
            const int col = wn * 64 + ni * 16 + lr;
            #pragma unroll
            for (int kk = 0; kk < 2; ++kk)
                bfr[ni][kk] = *(const short8v*)(Bs + col * 64 + (((kk * 4 + lg) ^ (col & 7)) * 8));
        }

        #pragma unroll
        for (int kk = 0; kk < 2; ++kk)
            #pragma unroll
            for (int mi = 0; mi < 4; ++mi)
                #pragma unroll
                for (int ni = 0; ni < 4; ++ni)
                    acc[mi][ni] = __builtin_amdgcn_mfma_f32_16x16x32_bf16(
                        af[mi][kk], bfr[ni][kk], acc[mi][ni], 0, 0, 0);

        __syncthreads();   // before next stage overwrites LDS
    }

    // ---- epilogue: C[row][col], row = A-frag lr index -> 4*lg+r ----
    #pragma unroll
    for (int mi = 0; mi < 4; ++mi) {
        #pragma unroll
        for (int r = 0; r < 4; ++r) {
            const size_t row = row0 + wm * 64 + mi * 16 + 4 * lg + r;
            #pragma unroll
            for (int ni = 0; ni < 4; ++ni) {
                const int col = col0 + wn * 64 + ni * 16 + lr;
                float v = acc[mi][ni][r];
                if constexpr (BIAS) v += bias[col];
                if constexpr (sizeof(OutT) == 2)
                    C[row * (size_t)Nd + col] = (OutT)f2bf(v);
                else
                    C[row * (size_t)Nd + col] = (OutT)v;
            }
        }
    }
}

// ---------------------------------------------------------------------------
// V transpose: qkv_bf V-section [b,n, 2D + h*64 + d] -> Vt[bh][d][n]  (bf16)
// ---------------------------------------------------------------------------
__global__ __launch_bounds__(256)
void transposeV(const unsigned short* __restrict__ qkvb, unsigned short* __restrict__ Vt) {
    __shared__ unsigned short t[64][68];
    const int bh = blockIdx.y, b = bh >> 4, h = bh & 15;
    const int n0 = blockIdx.x * 64;
    const int tid = threadIdx.x;

    #pragma unroll
    for (int i = 0; i < 4; ++i) {
        int key = (tid >> 4) + 16 * i, d0 = (tid & 15) * 4;
        us4 v = *(const us4*)(qkvb + (size_t)(b * N + n0 + key) * K3 + 2 * D + h * 64 + d0);
        *(us4*)&t[key][d0] = v;
    }
    __syncthreads();
    #pragma unroll
    for (int i = 0; i < 4; ++i) {
        int d = (tid >> 4) + 16 * i, k0 = (tid & 15) * 4;
        us4 v = { t[k0][d], t[k0 + 1][d], t[k0 + 2][d], t[k0 + 3][d] };
        *(us4*)(Vt + ((size_t)bh * 64 + d) * N + n0 + k0) = v;
    }
}

// ---------------------------------------------------------------------------
// MFMA bf16 flash attention (bf16 output).
// ---------------------------------------------------------------------------
__global__ __launch_bounds__(256)
void attn_mfma(const unsigned short* __restrict__ qkvb,
               const unsigned short* __restrict__ Vt,
               unsigned short* __restrict__ out) {
    __shared__ unsigned short K_lds[64 * 64];
    __shared__ unsigned short V_lds[64 * 64];
    __shared__ unsigned short P_lds[4 * 16 * 64];

    const int tid  = threadIdx.x;
    const int lane = tid & 63;
    const int w    = tid >> 6;
    const int lr   = lane & 15;
    const int lg   = lane >> 4;
    const int bh   = blockIdx.y, b = bh >> 4, h = bh & 15;
    const int q0   = blockIdx.x * 64;

    short8v qa[2];
    {
        const unsigned short* qrow =
            qkvb + (size_t)(b * N + q0 + w * 16 + lr) * K3 + h * 64 + lg * 8;
        qa[0] = *(const short8v*)(qrow);
        qa[1] = *(const short8v*)(qrow + 32);
    }

    f32x4 oacc[4] = {};
    float mrow[4], lrow[4];
    #pragma unroll
    for (int r = 0; r < 4; ++r) { mrow[r] = -1e30f; lrow[r] = 0.f; }

    const unsigned short* kbase  = qkvb + (size_t)b * N * K3 + D + h * 64;
    const unsigned short* vtbase = Vt + (size_t)bh * 64 * N;

    for (int kt = 0; kt < N; kt += 64) {
        __syncthreads();
        #pragma unroll
        for (int i = 0; i < 2; ++i) {
            int cc = tid + 256 * i;
            int row = cc >> 3, blk = cc & 7;
            short8v kv = *(const short8v*)(kbase + (size_t)(kt + row) * K3 + blk * 8);
            *(short8v*)(K_lds + row * 64 + ((blk ^ (row & 7)) * 8)) = kv;
            short8v vv = *(const short8v*)(vtbase + (size_t)row * N + kt + blk * 8);
            *(short8v*)(V_lds + row * 64 + ((blk ^ (row & 7)) * 8)) = vv;
        }
        __syncthreads();

        f32x4 sacc[4] = {};
        #pragma unroll
        for (int sj = 0; sj < 4; ++sj) {
            const int key = 16 * sj + lr;
            #pragma unroll
            for (int ks = 0; ks < 2; ++ks) {
                short8v kb = *(const short8v*)(K_lds + key * 64 +
                                               (((4 * ks + lg) ^ (key & 7)) * 8));
                sacc[sj] = __builtin_amdgcn_mfma_f32_16x16x32_bf16(qa[ks], kb, sacc[sj], 0, 0, 0);
            }
        }

        float pm[4], alpha[4];
        #pragma unroll
        for (int r = 0; r < 4; ++r) {
            float mt = fmaxf(fmaxf(sacc[0][r], sacc[1][r]), fmaxf(sacc[2][r], sacc[3][r]));
            #pragma unroll
            for (int off = 8; off >= 1; off >>= 1)
                mt = fmaxf(mt, __shfl_xor(mt, off));
            pm[r] = mt;
        }
        #pragma unroll
        for (int r = 0; r < 4; ++r) {
            float mn = fmaxf(mrow[r], pm[r]);
            alpha[r] = __expf((mrow[r] - mn) * 0.125f);
            mrow[r] = mn;
        }
        float psum[4] = {0.f, 0.f, 0.f, 0.f};
        #pragma unroll
        for (int sj = 0; sj < 4; ++sj) {
            #pragma unroll
            for (int r = 0; r < 4; ++r) {
                float p = __expf((sacc[sj][r] - mrow[r]) * 0.125f);
                psum[r] += p;
                const int row = 4 * lg + r, key = 16 * sj + lr;
                P_lds[w * 1024 + row * 64 + (((key >> 3) ^ (row & 7)) * 8) + (key & 7)] = f2bf(p);
            }
        }
        #pragma unroll
        for (int r = 0; r < 4; ++r) {
            float ps = psum[r];
            #pragma unroll
            for (int off = 8; off >= 1; off >>= 1)
                ps += __shfl_xor(ps, off);
            lrow[r] = lrow[r] * alpha[r] + ps;
            #pragma unroll
            for (int dj = 0; dj < 4; ++dj) oacc[dj][r] *= alpha[r];
        }

        #pragma unroll
        for (int ks = 0; ks < 2; ++ks) {
            short8v pa = *(const short8v*)(P_lds + w * 1024 + lr * 64 +
                                           (((4 * ks + lg) ^ (lr & 7)) * 8));
            #pragma unroll
            for (int dj = 0; dj < 4; ++dj) {
                const int d = 16 * dj + lr;
                short8v vb = *(const short8v*)(V_lds + d * 64 +
                                               (((4 * ks + lg) ^ (d & 7)) * 8));
                oacc[dj] = __builtin_amdgcn_mfma_f32_16x16x32_bf16(pa, vb, oacc[dj], 0, 0, 0);
            }
        }
    }

    #pragma unroll
    for (int r = 0; r < 4; ++r) {
        const float inv = 1.0f / lrow[r];
        const int q = q0 + w * 16 + 4 * lg + r;
        #pragma unroll
        for (int dj = 0; dj < 4; ++dj)
            out[((size_t)b * N + q) * D + h * 64 + 16 * dj + lr] = f2bf(oacc[dj][r] * inv);
    }
}

// ---------------------------------------------------------------------------
// prep (cvt x, transpose W) -> QKV MFMA GEMM -> V transpose -> MFMA flash attn
// -> proj MFMA GEMM (+bias, fp32 out)
// ws: x_bf 16MB | Wqkv_t 6MB | Wproj_t 2MB | qkv_bf 48MB | Vt 16MB | ao_bf 16MB
// ---------------------------------------------------------------------------
extern "C" void kernel_launch(void* const* d_in, const int* in_sizes, int n_in,
                              void* d_out, int out_size, void* d_ws, size_t ws_size,
                              hipStream_t stream) {
    const float* x     = (const float*)d_in[0];
    const float* Wqkv  = (const float*)d_in[1];
    const float* Wproj = (const float*)d_in[2];
    const float* bproj = (const float*)d_in[3];
    float* outp = (float*)d_out;

    unsigned short* x_bf    = (unsigned short*)d_ws;                 // M x D
    unsigned short* Wqkv_t  = x_bf + (size_t)M * D;                  // K3 x D
    unsigned short* Wproj_t = Wqkv_t + (size_t)K3 * D;               // D x D
    unsigned short* qkv_bf  = Wproj_t + (size_t)D * D;               // M x K3
    unsigned short* Vtp     = qkv_bf + (size_t)M * K3;               // BH x HD x N
    unsigned short* ao_bf   = Vtp + (size_t)B * H * HD * N;          // M x D

    cvt_bf16<<<(M * D / 8 + 255) / 256, 256, 0, stream>>>(x, x_bf, M * D / 8);
    transpose_w<<<dim3(K3 / 64, D / 64), 256, 0, stream>>>(Wqkv, Wqkv_t, D, K3);
    transpose_w<<<dim3(D / 64, D / 64), 256, 0, stream>>>(Wproj, Wproj_t, D, D);

    dim3 g1(K3 / 128, M / 128);
    gemm_bf16<false, unsigned short><<<g1, 256, 0, stream>>>(x_bf, Wqkv_t, qkv_bf, nullptr, M, K3, D);

    dim3 g2(N / 64, B * H);
    transposeV<<<g2, 256, 0, stream>>>(qkv_bf, Vtp);

    dim3 g3(N / 64, B * H);
    attn_mfma<<<g3, 256, 0, stream>>>(qkv_bf, Vtp, ao_bf);

    dim3 g4(D / 128, M / 128);
    gemm_bf16<true, float><<<g4, 256, 0, stream>>>(ao_bf, Wproj_t, outp, bproj, M, D, D);
}

// Round 7
// 317.160 us; speedup vs baseline: 16.9977x; 1.3132x over previous
//
#include <hip/hip_runtime.h>
#include <hip/hip_bf16.h>

// Problem constants (fixed by the reference)
constexpr int B  = 4;
constexpr int N  = 2048;
constexpr int D  = 1024;
constexpr int H  = 16;
constexpr int HD = 64;            // head dim
constexpr int M  = B * N;         // 8192 rows
constexpr int K3 = 3 * D;         // 3072

typedef __attribute__((ext_vector_type(8))) short  short8v;  // 8 bf16 in 4 VGPRs
typedef __attribute__((ext_vector_type(4))) float  f32x4;
typedef __attribute__((ext_vector_type(4))) unsigned short us4;

__device__ inline unsigned short f2bf(float f) {   // fp32 -> bf16 bits, RNE
    union { float f; unsigned u; } x{f};
    unsigned r = x.u + 0x7fffu + ((x.u >> 16) & 1u);
    return (unsigned short)(r >> 16);
}

__device__ __forceinline__ void gload_lds16(const unsigned short* g, unsigned short* l) {
    __builtin_amdgcn_global_load_lds(
        (const __attribute__((address_space(1))) void*)g,
        (__attribute__((address_space(3))) void*)l, 16, 0, 0);
}

// ---------------------------------------------------------------------------
// fp32 -> bf16 elementwise (8 elems/thread)
// ---------------------------------------------------------------------------
__global__ __launch_bounds__(256)
void cvt_bf16(const float* __restrict__ in, unsigned short* __restrict__ outp, int n8) {
    int i = blockIdx.x * 256 + threadIdx.x;
    if (i >= n8) return;
    f32x4 a = *(const f32x4*)(in + (size_t)i * 8);
    f32x4 b = *(const f32x4*)(in + (size_t)i * 8 + 4);
    short8v v;
    #pragma unroll
    for (int j = 0; j < 4; ++j) { v[j] = (short)f2bf(a[j]); v[4 + j] = (short)f2bf(b[j]); }
    *(short8v*)(outp + (size_t)i * 8) = v;
}

// ---------------------------------------------------------------------------
// W [Kd][Nd] fp32  ->  Wt [Nd][Kd] bf16   (64x64 tiles via LDS)
// ---------------------------------------------------------------------------
__global__ __launch_bounds__(256)
void transpose_w(const float* __restrict__ W, unsigned short* __restrict__ Wt,
                 int Kd, int Nd) {
    __shared__ unsigned short t[64][68];
    const int k0 = blockIdx.y * 64, n0 = blockIdx.x * 64;
    const int tid = threadIdx.x;
    #pragma unroll
    for (int i = 0; i < 4; ++i) {
        int k = (tid >> 4) + 16 * i, nn = (tid & 15) * 4;
        f32x4 v = *(const f32x4*)(W + (size_t)(k0 + k) * Nd + n0 + nn);
        #pragma unroll
        for (int j = 0; j < 4; ++j) t[k][nn + j] = f2bf(v[j]);
    }
    __syncthreads();
    #pragma unroll
    for (int i = 0; i < 4; ++i) {
        int n = (tid >> 4) + 16 * i, kk = (tid & 15) * 4;
        us4 v = { t[kk][n], t[kk + 1][n], t[kk + 2][n], t[kk + 3][n] };
        *(us4*)(Wt + (size_t)(n0 + n) * Kd + k0 + kk) = v;
    }
}

// ---------------------------------------------------------------------------
// bf16 MFMA GEMM (m97 structure): C[Md][Nd] = A[Md][Kd] @ Bt[Nd][Kd]^T (+bias)
// 128x128 tile, BK=64, 256 thr = 4 waves (2x2), wave = 64x64 quadrant.
// ---------------------------------------------------------------------------
template <bool BIAS, typename OutT>
__global__ __launch_bounds__(256)
void gemm_bf16(const unsigned short* __restrict__ A,   // [Md][Kd]
               const unsigned short* __restrict__ Bt,  // [Nd][Kd]
               OutT* __restrict__ C, const float* __restrict__ bias,
               int Md, int Nd, int Kd) {
    __shared__ unsigned short As[128 * 64];
    __shared__ unsigned short Bs[128 * 64];

    const int tid  = threadIdx.x;
    const int lane = tid & 63;
    const int w    = tid >> 6;
    const int lr   = lane & 15;
    const int lg   = lane >> 4;
    const int wm   = w >> 1, wn = w & 1;
    const int row0 = blockIdx.y * 128;
    const int col0 = blockIdx.x * 128;

    f32x4 acc[4][4] = {};   // [mi][ni]

    for (int k0 = 0; k0 < Kd; k0 += 64) {
        #pragma unroll
        for (int it = 0; it < 4; ++it) {
            const int c    = (it * 4 + w) * 64 + lane;   // chunk 0..1023
            const int row  = c >> 3, slot = c & 7;
            const int gs   = (slot ^ (row & 7)) * 8;     // pre-swizzled source
            gload_lds16(A  + (size_t)(row0 + row) * Kd + k0 + gs, As + c * 8);
            gload_lds16(Bt + (size_t)(col0 + row) * Kd + k0 + gs, Bs + c * 8);
        }
        asm volatile("s_waitcnt vmcnt(0)" ::: "memory");
        __syncthreads();

        short8v af[4][2], bfr[4][2];
        #pragma unroll
        for (int mi = 0; mi < 4; ++mi) {
            const int row = wm * 64 + mi * 16 + lr;
            #pragma unroll
            for (int kk = 0; kk < 2; ++kk)
                af[mi][kk] = *(const short8v*)(As + row * 64 + (((kk * 4 + lg) ^ (row & 7)) * 8));
        }
        #pragma unroll
        for (int ni = 0; ni < 4; ++ni) {
            const int col = wn * 64 + ni * 16 + lr;
            #pragma unroll
            for (int kk = 0; kk < 2; ++kk)
                bfr[ni][kk] = *(const short8v*)(Bs + col * 64 + (((kk * 4 + lg) ^ (col & 7)) * 8));
        }

        #pragma unroll
        for (int kk = 0; kk < 2; ++kk)
            #pragma unroll
            for (int mi = 0; mi < 4; ++mi)
                #pragma unroll
                for (int ni = 0; ni < 4; ++ni)
                    acc[mi][ni] = __builtin_amdgcn_mfma_f32_16x16x32_bf16(
                        af[mi][kk], bfr[ni][kk], acc[mi][ni], 0, 0, 0);

        __syncthreads();
    }

    #pragma unroll
    for (int mi = 0; mi < 4; ++mi) {
        #pragma unroll
        for (int r = 0; r < 4; ++r) {
            const size_t row = row0 + wm * 64 + mi * 16 + 4 * lg + r;
            #pragma unroll
            for (int ni = 0; ni < 4; ++ni) {
                const int col = col0 + wn * 64 + ni * 16 + lr;
                float v = acc[mi][ni][r];
                if constexpr (BIAS) v += bias[col];
                if constexpr (sizeof(OutT) == 2)
                    C[row * (size_t)Nd + col] = (OutT)f2bf(v);
                else
                    C[row * (size_t)Nd + col] = (OutT)v;
            }
        }
    }
}

// ---------------------------------------------------------------------------
// V transpose: qkv_bf V-section [b,n, 2D + h*64 + d] -> Vt[bh][d][n]  (bf16)
// ---------------------------------------------------------------------------
__global__ __launch_bounds__(256)
void transposeV(const unsigned short* __restrict__ qkvb, unsigned short* __restrict__ Vt) {
    __shared__ unsigned short t[64][68];
    const int bh = blockIdx.y, b = bh >> 4, h = bh & 15;
    const int n0 = blockIdx.x * 64;
    const int tid = threadIdx.x;

    #pragma unroll
    for (int i = 0; i < 4; ++i) {
        int key = (tid >> 4) + 16 * i, d0 = (tid & 15) * 4;
        us4 v = *(const us4*)(qkvb + (size_t)(b * N + n0 + key) * K3 + 2 * D + h * 64 + d0);
        *(us4*)&t[key][d0] = v;
    }
    __syncthreads();
    #pragma unroll
    for (int i = 0; i < 4; ++i) {
        int d = (tid >> 4) + 16 * i, k0 = (tid & 15) * 4;
        us4 v = { t[k0][d], t[k0 + 1][d], t[k0 + 2][d], t[k0 + 3][d] };
        *(us4*)(Vt + ((size_t)bh * 64 + d) * N + n0 + k0) = v;
    }
}

// ---------------------------------------------------------------------------
// MFMA bf16 flash attention, SWAPPED QK^T (row-local softmax).
// Grid (N/64, B*H), 256 thr = 4 waves; each wave owns 16 q-rows.
// S^T = mfma(K, Q): lane holds S[key=16sj+4lg+r][q=lr] -> all 16 scores are
// ONE q-row. Row max: 15 in-lane fmax + shfl_xor(16,32). Row sum: per-lane
// accumulation, single cross-lane reduce at end. Defer-max THR=64 raw
// (=8 nat-log). P packed via v_cvt_pk_bf16_f32, 8B ds_writes. PV unchanged.
// ---------------------------------------------------------------------------
__global__ __launch_bounds__(256)
void attn_mfma(const unsigned short* __restrict__ qkvb,
               const unsigned short* __restrict__ Vt,
               unsigned short* __restrict__ out) {
    __shared__ unsigned short K_lds[64 * 64];     // [key][d] swizzled
    __shared__ unsigned short V_lds[64 * 64];     // [d][key] swizzled
    __shared__ unsigned short P_lds[4 * 16 * 64]; // per-wave [q][key] swizzled

    const int tid  = threadIdx.x;
    const int lane = tid & 63;
    const int w    = tid >> 6;
    const int lr   = lane & 15;
    const int lg   = lane >> 4;
    const int bh   = blockIdx.y, b = bh >> 4, h = bh & 15;
    const int q0   = blockIdx.x * 64;

    // Q fragments (B-operand: col=lr=q-row, k=8*lg+e), 2 k-steps over d=64
    short8v qa[2];
    {
        const unsigned short* qrow =
            qkvb + (size_t)(b * N + q0 + w * 16 + lr) * K3 + h * 64 + lg * 8;
        qa[0] = *(const short8v*)(qrow);
        qa[1] = *(const short8v*)(qrow + 32);
    }

    f32x4 oacc[4] = {};
    float mrow = -1e30f;   // running max for q-row lr (per lane)
    float lsum = 0.f;      // per-lane partial sum for q-row lr

    const unsigned short* kbase  = qkvb + (size_t)b * N * K3 + D + h * 64;
    const unsigned short* vtbase = Vt + (size_t)bh * 64 * N;

    for (int kt = 0; kt < N; kt += 64) {
        __syncthreads();                      // previous tile fully consumed
        // ---- stage K,V via global_load_lds (pre-swizzled source, rule 21) ----
        #pragma unroll
        for (int i = 0; i < 2; ++i) {
            const int c   = tid + 256 * i;    // wave-contiguous chunks
            const int row = c >> 3, slot = c & 7;
            const int gs  = (slot ^ (row & 7)) * 8;
            gload_lds16(kbase  + (size_t)(kt + row) * K3 + gs, K_lds + c * 8);
            gload_lds16(vtbase + (size_t)row * N + kt + gs,    V_lds + c * 8);
        }
        asm volatile("s_waitcnt vmcnt(0)" ::: "memory");
        __syncthreads();

        // ---- S^T = K @ Q^T : sacc[sj][r] = S[key=16sj+4lg+r][q=lr] ----
        f32x4 sacc[4] = {};
        #pragma unroll
        for (int sj = 0; sj < 4; ++sj) {
            const int key = 16 * sj + lr;
            #pragma unroll
            for (int ks = 0; ks < 2; ++ks) {
                short8v kb = *(const short8v*)(K_lds + key * 64 +
                                               (((4 * ks + lg) ^ (key & 7)) * 8));
                sacc[sj] = __builtin_amdgcn_mfma_f32_16x16x32_bf16(kb, qa[ks], sacc[sj], 0, 0, 0);
            }
        }

        // ---- row-local online softmax ----
        float pmax = fmaxf(fmaxf(sacc[0][0], sacc[0][1]), fmaxf(sacc[0][2], sacc[0][3]));
        #pragma unroll
        for (int sj = 1; sj < 4; ++sj)
            pmax = fmaxf(pmax, fmaxf(fmaxf(sacc[sj][0], sacc[sj][1]),
                                     fmaxf(sacc[sj][2], sacc[sj][3])));
        pmax = fmaxf(pmax, __shfl_xor(pmax, 16));
        pmax = fmaxf(pmax, __shfl_xor(pmax, 32));

        if (!__all(pmax - mrow <= 64.0f)) {   // defer-max: rescale only on growth
            const float mnew  = fmaxf(mrow, pmax);
            const float alpha = __expf((mrow - mnew) * 0.125f);
            mrow = mnew;
            lsum *= alpha;
            #pragma unroll
            for (int r = 0; r < 4; ++r) {
                const float ar = __shfl(alpha, 4 * lg + r);
                #pragma unroll
                for (int dj = 0; dj < 4; ++dj) oacc[dj][r] *= ar;
            }
        }

        const float m8 = mrow * 0.125f;
        #pragma unroll
        for (int sj = 0; sj < 4; ++sj) {
            const float p0 = __expf(fmaf(sacc[sj][0], 0.125f, -m8));
            const float p1 = __expf(fmaf(sacc[sj][1], 0.125f, -m8));
            const float p2 = __expf(fmaf(sacc[sj][2], 0.125f, -m8));
            const float p3 = __expf(fmaf(sacc[sj][3], 0.125f, -m8));
            lsum += (p0 + p1) + (p2 + p3);
            unsigned pk0, pk1;
            asm("v_cvt_pk_bf16_f32 %0, %1, %2" : "=v"(pk0) : "v"(p0), "v"(p1));
            asm("v_cvt_pk_bf16_f32 %0, %1, %2" : "=v"(pk1) : "v"(p2), "v"(p3));
            // write keys 16sj+4lg+{0..3} of row lr: 16B-slot t = 2sj + (lg>>1)
            const int t = 2 * sj + (lg >> 1);
            uint2* dst = (uint2*)(P_lds + w * 1024 + lr * 64 +
                                  ((t ^ (lr & 7)) * 8) + 4 * (lg & 1));
            *dst = make_uint2(pk0, pk1);
        }

        // ---- O += P @ V  (pa: row=lr=q, keys 32ks+8lg..+7 -> slot 4ks+lg) ----
        #pragma unroll
        for (int ks = 0; ks < 2; ++ks) {
            short8v pa = *(const short8v*)(P_lds + w * 1024 + lr * 64 +
                                           (((4 * ks + lg) ^ (lr & 7)) * 8));
            #pragma unroll
            for (int dj = 0; dj < 4; ++dj) {
                const int d = 16 * dj + lr;
                short8v vb = *(const short8v*)(V_lds + d * 64 +
                                               (((4 * ks + lg) ^ (d & 7)) * 8));
                oacc[dj] = __builtin_amdgcn_mfma_f32_16x16x32_bf16(pa, vb, oacc[dj], 0, 0, 0);
            }
        }
    }

    // ---- epilogue: finish row sums, normalize, store bf16 ----
    float ltot = lsum;
    ltot += __shfl_xor(ltot, 16);
    ltot += __shfl_xor(ltot, 32);
    const float linv = 1.0f / ltot;          // valid for q-row lr
    #pragma unroll
    for (int r = 0; r < 4; ++r) {
        const float inv = __shfl(linv, 4 * lg + r);
        const int q = q0 + w * 16 + 4 * lg + r;
        #pragma unroll
        for (int dj = 0; dj < 4; ++dj)
            out[((size_t)b * N + q) * D + h * 64 + 16 * dj + lr] = f2bf(oacc[dj][r] * inv);
    }
}

// ---------------------------------------------------------------------------
// prep (cvt x, transpose W) -> QKV MFMA GEMM -> V transpose -> MFMA flash attn
// -> proj MFMA GEMM (+bias, fp32 out)
// ws: x_bf 16MB | Wqkv_t 6MB | Wproj_t 2MB | qkv_bf 48MB | Vt 16MB | ao_bf 16MB
// ---------------------------------------------------------------------------
extern "C" void kernel_launch(void* const* d_in, const int* in_sizes, int n_in,
                              void* d_out, int out_size, void* d_ws, size_t ws_size,
                              hipStream_t stream) {
    const float* x     = (const float*)d_in[0];
    const float* Wqkv  = (const float*)d_in[1];
    const float* Wproj = (const float*)d_in[2];
    const float* bproj = (const float*)d_in[3];
    float* outp = (float*)d_out;

    unsigned short* x_bf    = (unsigned short*)d_ws;                 // M x D
    unsigned short* Wqkv_t  = x_bf + (size_t)M * D;                  // K3 x D
    unsigned short* Wproj_t = Wqkv_t + (size_t)K3 * D;               // D x D
    unsigned short* qkv_bf  = Wproj_t + (size_t)D * D;               // M x K3
    unsigned short* Vtp     = qkv_bf + (size_t)M * K3;               // BH x HD x N
    unsigned short* ao_bf   = Vtp + (size_t)B * H * HD * N;          // M x D

    cvt_bf16<<<(M * D / 8 + 255) / 256, 256, 0, stream>>>(x, x_bf, M * D / 8);
    transpose_w<<<dim3(K3 / 64, D / 64), 256, 0, stream>>>(Wqkv, Wqkv_t, D, K3);
    transpose_w<<<dim3(D / 64, D / 64), 256, 0, stream>>>(Wproj, Wproj_t, D, D);

    dim3 g1(K3 / 128, M / 128);
    gemm_bf16<false, unsigned short><<<g1, 256, 0, stream>>>(x_bf, Wqkv_t, qkv_bf, nullptr, M, K3, D);

    dim3 g2(N / 64, B * H);
    transposeV<<<g2, 256, 0, stream>>>(qkv_bf, Vtp);

    dim3 g3(N / 64, B * H);
    attn_mfma<<<g3, 256, 0, stream>>>(qkv_bf, Vtp, ao_bf);

    dim3 g4(D / 128, M / 128);
    gemm_bf16<true, float><<<g4, 256, 0, stream>>>(ao_bf, Wproj_t, outp, bproj, M, D, D);
}